// Round 5
// baseline (108.289 us; speedup 1.0000x reference)
//
#include <hip/hip_runtime.h>

#define BB 512
#define TT 30
#define HH 41
#define WFW 40
#define NSEC 9
#define SECLEN 4
#define NF 50
#define KH 6
#define THRESH 23.0f
#define NBT (BB*TT)                 // 15360 (b,t) rows
#define WIN_CNT (NSEC*BB)           // 4608 winners precede pots in d_out
#define BT_BLK 64                   // bt rows per block
#define NBTBLK (NBT/BT_BLK)         // 240 (0 mod 8 -> same-XCD x reuse across sections)
#define BBYTES 32768                // one section's B fragments
#define WSW_BYTES (NSEC*4*8*64*16)  // 294912: W as B-fragments, bf16
#define SPK_BYTES (NSEC*NBT*NF)     // 6912000: spike byte per (i,bt,f)

#define GLOBAL_AS __attribute__((address_space(1)))
#define LDS_AS    __attribute__((address_space(3)))

typedef __attribute__((ext_vector_type(8))) short short8;     // 8 bf16 = 4 VGPR
typedef __attribute__((ext_vector_type(4))) float f32x4;
typedef __attribute__((ext_vector_type(4))) unsigned uint4v;

// ---------------------------------------------------------------------------
// Pre-kernel: W fp32 -> bf16 B-fragment layout in ws.
// Fragment (i,nt,kc): lane l holds B[k][f], f = nt*16+(l&15), k = 32kc+8*(l>>4)+j.
// Zero for f>=50 or k>=240 (K padded 240->256, N padded 50->64).
// ---------------------------------------------------------------------------
__global__ __launch_bounds__(256) void wconv_kernel(const float* __restrict__ W,
                                                    unsigned char* __restrict__ wsw)
{
    int gid  = blockIdx.x * 256 + threadIdx.x;      // 18432 total
    int frag = gid >> 6, l = gid & 63;
    int i    = frag >> 5, rem = frag & 31;
    int nt   = rem >> 3,  kc  = rem & 7;
    int f    = nt * 16 + (l & 15);
    int kb   = kc * 32 + (l >> 4) * 8;
    unsigned d0 = 0, d1 = 0, d2 = 0, d3 = 0;
    if (f < NF && kb < KH * WFW) {
        const float* src = W + (size_t)(i * NF + f) * (KH * WFW) + kb;
        float4 v0 = ((const float4*)src)[0];
        float4 v1 = ((const float4*)src)[1];
        float vv[8] = {v0.x, v0.y, v0.z, v0.w, v1.x, v1.y, v1.z, v1.w};
        unsigned r[8];
        #pragma unroll
        for (int j = 0; j < 8; ++j) {
            unsigned a = __float_as_uint(vv[j]);
            r[j] = (a + 0x7FFFu + ((a >> 16) & 1u)) >> 16;   // RNE to bf16
        }
        d0 = r[0] | (r[1] << 16); d1 = r[2] | (r[3] << 16);
        d2 = r[4] | (r[5] << 16); d3 = r[6] | (r[7] << 16);
    }
    ((uint4*)wsw)[gid] = make_uint4(d0, d1, d2, d3);
}

// Pack 8 fp32 (values 0/1) -> short8 bf16 by truncation (exact for 0/1).
__device__ __forceinline__ short8 pack_bf16_trunc(float4 lo, float4 hi)
{
    unsigned u0 = __float_as_uint(lo.x), u1 = __float_as_uint(lo.y);
    unsigned u2 = __float_as_uint(lo.z), u3 = __float_as_uint(lo.w);
    unsigned u4 = __float_as_uint(hi.x), u5 = __float_as_uint(hi.y);
    unsigned u6 = __float_as_uint(hi.z), u7 = __float_as_uint(hi.w);
    uint4v p;
    p.x = (u0 >> 16) | (u1 & 0xFFFF0000u);
    p.y = (u2 >> 16) | (u3 & 0xFFFF0000u);
    p.z = (u4 >> 16) | (u5 & 0xFFFF0000u);
    p.w = (u6 >> 16) | (u7 & 0xFFFF0000u);
    return __builtin_bit_cast(short8, p);
}

// ---------------------------------------------------------------------------
// Main kernel: block = (section i, 64 bt). NO x staging: A-fragments loaded
// per-lane straight from global (L3-resident) as 2x dwordx4 + trunc-pack.
// LDS holds only B (32 KB, global_load_lds) -> 4 blocks/CU, no main-loop
// barriers. Per kc: 4 B ds_read + 4 x (2 global loads + pack + 4 MFMA).
// ---------------------------------------------------------------------------
template<bool WRITE_SPK>
__global__ __launch_bounds__(256, 4) void pots_mfma(const float* __restrict__ x,
                                                    const unsigned char* __restrict__ wsw,
                                                    float* __restrict__ out,
                                                    unsigned char* __restrict__ spk)
{
    __shared__ alignas(16) unsigned char Bs[BBYTES];   // 32 KB only
    const int tid = threadIdx.x;
    const int blk = blockIdx.x;
    const int i   = blk / NBTBLK;                      // section
    const int bt0 = (blk - i * NBTBLK) * BT_BLK;
    const int l   = tid & 63, wid = tid >> 6;

    // ---- issue B-fragment copies (32 x 1KB, 8 per wave) ----
    {
        const unsigned char* wsec = wsw + (size_t)i * BBYTES + (size_t)l * 16;
        #pragma unroll
        for (int j = 0; j < 8; ++j) {
            int f = wid * 8 + j;
            __builtin_amdgcn_global_load_lds(
                (const GLOBAL_AS void*)(wsec + f * 1024),
                (LDS_AS void*)(Bs + f * 1024), 16, 0, 0);
        }
    }

    // ---- per-lane A addressing: row = l&15 -> (bt_in=(l>>2)&3, s=l&3); q=l>>4
    const int q = l >> 4;
    const float* ab0 = x + (size_t)(bt0 + wid * 16 + ((l >> 2) & 3)) * (HH * WFW)
                     + i * (SECLEN * WFW) + (l & 3) * WFW + q * 8;
    const float* ab1 = ab0 + 1 * 4 * (HH * WFW);
    const float* ab2 = ab0 + 2 * 4 * (HH * WFW);
    const float* ab3 = ab0 + 3 * 4 * (HH * WFW);
    const unsigned char* bb = Bs + (unsigned)l * 16;

    f32x4 acc[4][4];
    #pragma unroll
    for (int r = 0; r < 4; ++r)
        #pragma unroll
        for (int nt = 0; nt < 4; ++nt)
            acc[r][nt] = (f32x4){0.f, 0.f, 0.f, 0.f};

    __syncthreads();   // B resident (drains vmcnt incl. global_load_lds)

    #pragma unroll
    for (int kc = 0; kc < 8; ++kc) {
        short8 b0 = *(const short8*)(bb + (0 * 8 + kc) * 1024);
        short8 b1 = *(const short8*)(bb + (1 * 8 + kc) * 1024);
        short8 b2 = *(const short8*)(bb + (2 * 8 + kc) * 1024);
        short8 b3 = *(const short8*)(bb + (3 * 8 + kc) * 1024);
        #pragma unroll
        for (int r = 0; r < 4; ++r) {
            const float* ar = (r == 0) ? ab0 : (r == 1) ? ab1 : (r == 2) ? ab2 : ab3;
            short8 a = __builtin_bit_cast(short8, (uint4v){0u, 0u, 0u, 0u});
            if (kc < 7 || q < 2) {   // kc==7, q>=2: k>=240 (B=0 there); avoid OOB
                float4 lo = ((const float4*)(ar + kc * 32))[0];
                float4 hi = ((const float4*)(ar + kc * 32))[1];
                a = pack_bf16_trunc(lo, hi);
            }
            acc[r][0] = __builtin_amdgcn_mfma_f32_16x16x32_bf16(a, b0, acc[r][0], 0, 0, 0);
            acc[r][1] = __builtin_amdgcn_mfma_f32_16x16x32_bf16(a, b1, acc[r][1], 0, 0, 0);
            acc[r][2] = __builtin_amdgcn_mfma_f32_16x16x32_bf16(a, b2, acc[r][2], 0, 0, 0);
            acc[r][3] = __builtin_amdgcn_mfma_f32_16x16x32_bf16(a, b3, acc[r][3], 0, 0, 0);
        }
    }

    // D layout: col = l&15 (f), rows 4q+reg = (bt_in=q, s=reg)
    const int f16 = l & 15;
    #pragma unroll
    for (int r = 0; r < 4; ++r) {
        const int btd = bt0 + wid * 16 + r * 4 + q;
        const size_t base = ((size_t)i * NBT + btd) * NF;
        #pragma unroll
        for (int nt = 0; nt < 4; ++nt) {
            int f = nt * 16 + f16;
            if (f < NF) {
                size_t o = base + f;
                *(float4*)(out + WIN_CNT + o * 4) =
                    make_float4(acc[r][nt][0], acc[r][nt][1], acc[r][nt][2], acc[r][nt][3]);
                if (WRITE_SPK) {
                    float m = fmaxf(fmaxf(acc[r][nt][0], acc[r][nt][1]),
                                    fmaxf(acc[r][nt][2], acc[r][nt][3]));
                    spk[o] = (m >= THRESH) ? (unsigned char)1 : (unsigned char)0;
                }
            }
        }
    }
}

// ---------------------------------------------------------------------------
// Winners from spike bytes. Verified formula: c=popcnt, first=min(30-c,29),
// fv=bit(first), total=c*(fv+30*any(fv)), first-occurrence argmax, -1 if <=0.
// ---------------------------------------------------------------------------
__global__ __launch_bounds__(64) void win_spk(const unsigned char* __restrict__ spk,
                                              float* __restrict__ out)
{
    const int blk = blockIdx.x;              // i*BB + b
    const int i = blk / BB, b = blk - i * BB;
    const int f = threadIdx.x;
    unsigned mask = 0u;
    if (f < NF) {
        const unsigned char* p = spk + (size_t)(i * NBT + b * TT) * NF + f;
        for (int t = 0; t < TT; ++t)
            if (p[(size_t)t * NF]) mask |= (1u << t);
    }
    int c     = __popc(mask);
    int first = TT - c; if (first > TT - 1) first = TT - 1;
    int fv    = (f < NF) ? (int)((mask >> first) & 1u) : 0;
    unsigned long long bal = __ballot(fv != 0);
    int v30 = (bal != 0ull) ? TT : 0;
    int tot = (f < NF) ? c * (fv + v30) : -1;
    int idx = f;
    for (int off = 32; off > 0; off >>= 1) {
        int ot = __shfl_xor(tot, off);
        int oi = __shfl_xor(idx, off);
        if (ot > tot || (ot == tot && oi < idx)) { tot = ot; idx = oi; }
    }
    if (f == 0) out[blk] = (float)((tot > 0) ? idx : -1);
}

// Fallback: winners straight from pots (if ws too small for spike buffer).
__global__ __launch_bounds__(64) void win_pots(float* __restrict__ out)
{
    const int blk = blockIdx.x;
    const int f   = threadIdx.x;
    const float* po = out + WIN_CNT + (size_t)blk * TT * NF * SECLEN;
    unsigned mask = 0u;
    if (f < NF) {
        for (int t = 0; t < TT; ++t) {
            const float4 v = *(const float4*)(po + ((size_t)t * NF + f) * SECLEN);
            float m = fmaxf(fmaxf(v.x, v.y), fmaxf(v.z, v.w));
            if (m >= THRESH) mask |= (1u << t);
        }
    }
    int c     = __popc(mask);
    int first = TT - c; if (first > TT - 1) first = TT - 1;
    int fv    = (f < NF) ? (int)((mask >> first) & 1u) : 0;
    unsigned long long bal = __ballot(fv != 0);
    int v30 = (bal != 0ull) ? TT : 0;
    int tot = (f < NF) ? c * (fv + v30) : -1;
    int idx = f;
    for (int off = 32; off > 0; off >>= 1) {
        int ot = __shfl_xor(tot, off);
        int oi = __shfl_xor(idx, off);
        if (ot > tot || (ot == tot && oi < idx)) { tot = ot; idx = oi; }
    }
    if (f == 0) out[blk] = (float)((tot > 0) ? idx : -1);
}

extern "C" void kernel_launch(void* const* d_in, const int* in_sizes, int n_in,
                              void* d_out, int out_size, void* d_ws, size_t ws_size,
                              hipStream_t stream)
{
    const float* x = (const float*)d_in[0];
    const float* W = (const float*)d_in[1];
    float* out = (float*)d_out;
    unsigned char* wsw = (unsigned char*)d_ws;
    unsigned char* spk = wsw + WSW_BYTES;
    const bool use_spk = ws_size >= (size_t)(WSW_BYTES + SPK_BYTES);

    wconv_kernel<<<(NSEC*4*8*64) / 256, 256, 0, stream>>>(W, wsw);
    if (use_spk) {
        pots_mfma<true><<<NSEC * NBTBLK, 256, 0, stream>>>(x, wsw, out, spk);
        win_spk<<<NSEC * BB, 64, 0, stream>>>(spk, out);
    } else {
        pots_mfma<false><<<NSEC * NBTBLK, 256, 0, stream>>>(x, wsw, out, nullptr);
        win_pots<<<NSEC * BB, 64, 0, stream>>>(out);
    }
}

// Round 6
// 62.061 us; speedup vs baseline: 1.7449x; 1.7449x over previous
//
#include <hip/hip_runtime.h>

#define BB 512
#define TT 30
#define HH 41
#define WFW 40
#define NSEC 9
#define SECLEN 4
#define NF 50
#define KH 6
#define THRESH 23.0f
#define NBT (BB*TT)                 // 15360 (b,t) rows
#define WIN_CNT (NSEC*BB)           // 4608 winners precede pots in d_out
#define BT_BLK 64                   // bt rows per block
#define NBTBLK (NBT/BT_BLK)         // 240 (0 mod 8 -> same-XCD x reuse across sections)
#define SLAB 752                    // bytes per bt slab: 376 bf16 (360 data + 16 K-pad)
#define XBYTES (BT_BLK*SLAB)        // 48128
#define WSW_BYTES (NSEC*4*8*64*16)  // 294912: W as B-fragments, bf16
#define SPK_BYTES (NSEC*NBT*NF)     // 6912000: spike byte per (i,bt,f)

typedef __attribute__((ext_vector_type(8))) short short8;   // 8 bf16 = 4 VGPR
typedef __attribute__((ext_vector_type(4))) float f32x4;

// ---------------------------------------------------------------------------
// Pre-kernel: W fp32 -> bf16 B-fragment layout in ws.
// Fragment (i,nt,kc): lane l holds B[k][f], f = nt*16+(l&15), k = 32kc+8*(l>>4)+j.
// ---------------------------------------------------------------------------
__global__ __launch_bounds__(256) void wconv_kernel(const float* __restrict__ W,
                                                    unsigned char* __restrict__ wsw)
{
    int gid  = blockIdx.x * 256 + threadIdx.x;      // 18432 total
    int frag = gid >> 6, l = gid & 63;
    int i    = frag >> 5, rem = frag & 31;
    int nt   = rem >> 3,  kc  = rem & 7;
    int f    = nt * 16 + (l & 15);
    int kb   = kc * 32 + (l >> 4) * 8;
    unsigned d0 = 0, d1 = 0, d2 = 0, d3 = 0;
    if (f < NF && kb < KH * WFW) {
        const float* src = W + (size_t)(i * NF + f) * (KH * WFW) + kb;
        float4 v0 = ((const float4*)src)[0];
        float4 v1 = ((const float4*)src)[1];
        float vv[8] = {v0.x, v0.y, v0.z, v0.w, v1.x, v1.y, v1.z, v1.w};
        unsigned r[8];
        #pragma unroll
        for (int j = 0; j < 8; ++j) {
            unsigned a = __float_as_uint(vv[j]);
            r[j] = (a + 0x7FFFu + ((a >> 16) & 1u)) >> 16;   // RNE to bf16
        }
        d0 = r[0] | (r[1] << 16); d1 = r[2] | (r[3] << 16);
        d2 = r[4] | (r[5] << 16); d3 = r[6] | (r[7] << 16);
    }
    ((uint4*)wsw)[gid] = make_uint4(d0, d1, d2, d3);
}

// ---------------------------------------------------------------------------
// Main kernel: block = (section i, 64 bt), 512 threads (8 waves).
// Waves = (mg 0..3 M-group of 16 bt, nh 0..1 N-half of 32 f). Per wave:
// acc[4][2] = 32 VGPR; per kc: 2 B global loads (L2) + 4 A ds_read_b128 +
// 8 MFMA. Low VGPR + 48KB LDS -> 3 blocks/CU = 24 waves/CU for latency hiding.
// ---------------------------------------------------------------------------
template<bool WRITE_SPK>
__global__ __launch_bounds__(512, 6) void pots_mfma(const float* __restrict__ x,
                                                    const unsigned char* __restrict__ wsw,
                                                    float* __restrict__ out,
                                                    unsigned char* __restrict__ spk)
{
    __shared__ alignas(16) unsigned char xs[XBYTES];   // 48128 B
    const int tid = threadIdx.x;
    const int blk = blockIdx.x;
    const int i   = blk / NBTBLK;                    // section
    const int bt0 = (blk - i * NBTBLK) * BT_BLK;

    // ---- stage x rows 4i..4i+8 (360 floats/bt) -> bf16 slabs, coalesced ----
    const float* xg = x + (size_t)bt0 * (HH * WFW) + i * SECLEN * WFW;
    #pragma unroll
    for (int it = 0; it < 12; ++it) {
        int idx = tid + it * 512;                    // float4 index, 64*90 total
        if (idx < BT_BLK * 90) {
            int bt = idx / 90, pos = idx - bt * 90;
            const float4 v = *(const float4*)(xg + (size_t)bt * (HH * WFW) + pos * 4);
            unsigned u0 = __float_as_uint(v.x), u1 = __float_as_uint(v.y);
            unsigned u2 = __float_as_uint(v.z), u3 = __float_as_uint(v.w);
            uint2 p;                                 // x in {0,1}: truncation exact
            p.x = (u0 >> 16) | (u1 & 0xFFFF0000u);
            p.y = (u2 >> 16) | (u3 & 0xFFFF0000u);
            *(uint2*)(xs + bt * SLAB + pos * 8) = p;
        }
    }
    if (tid < 128) {   // zero K-pad elems 360..375 of each slab
        int bt = tid >> 1, part = tid & 1;
        *(uint4*)(xs + bt * SLAB + 720 + part * 16) = make_uint4(0, 0, 0, 0);
    }
    __syncthreads();

    const int l   = tid & 63, wid = tid >> 6;
    const int mg  = wid & 3;                         // M-group (16 bt)
    const int nh  = wid >> 2;                        // N-half (32 f)
    const int q   = l >> 4;                          // A: k-subblock; D: bt-in-tile
    const int f16 = l & 15;
    // A-frag row (l&15) = 4*((l>>2)&3) + (l&3)
    const unsigned abase = (unsigned)(mg * 16 + ((l >> 2) & 3)) * SLAB
                         + 80u * (l & 3) + 16u * q;

    f32x4 acc[4][2];
    #pragma unroll
    for (int r = 0; r < 4; ++r) {
        acc[r][0] = (f32x4){0.f, 0.f, 0.f, 0.f};
        acc[r][1] = (f32x4){0.f, 0.f, 0.f, 0.f};
    }

    const unsigned char* wbase = wsw + (size_t)i * 32768
                               + (size_t)(nh * 2) * 8192 + (size_t)l * 16;
    #pragma unroll
    for (int kc = 0; kc < 8; ++kc) {
        short8 b0 = *(const short8*)(wbase + kc * 1024);
        short8 b1 = *(const short8*)(wbase + 8192 + kc * 1024);
        #pragma unroll
        for (int r = 0; r < 4; ++r) {
            short8 a = *(const short8*)(xs + abase + r * 4 * SLAB + kc * 64);
            acc[r][0] = __builtin_amdgcn_mfma_f32_16x16x32_bf16(a, b0, acc[r][0], 0, 0, 0);
            acc[r][1] = __builtin_amdgcn_mfma_f32_16x16x32_bf16(a, b1, acc[r][1], 0, 0, 0);
        }
    }

    // D layout: col=f16 (f within n-tile), rows 4q+reg = (bt_in=q, s=reg)
    #pragma unroll
    for (int r = 0; r < 4; ++r) {
        const int btd = bt0 + mg * 16 + r * 4 + q;
        const size_t base = ((size_t)i * NBT + btd) * NF;
        #pragma unroll
        for (int jn = 0; jn < 2; ++jn) {
            int f = (nh * 2 + jn) * 16 + f16;
            if (f < NF) {
                size_t o = base + f;
                *(float4*)(out + WIN_CNT + o * 4) =
                    make_float4(acc[r][jn][0], acc[r][jn][1], acc[r][jn][2], acc[r][jn][3]);
                if (WRITE_SPK) {
                    float m = fmaxf(fmaxf(acc[r][jn][0], acc[r][jn][1]),
                                    fmaxf(acc[r][jn][2], acc[r][jn][3]));
                    spk[o] = (m >= THRESH) ? (unsigned char)1 : (unsigned char)0;
                }
            }
        }
    }
}

// ---------------------------------------------------------------------------
// Winners from spike bytes. Verified formula: c=popcnt, first=min(30-c,29),
// fv=bit(first), total=c*(fv+30*any(fv)), first-occurrence argmax, -1 if <=0.
// ---------------------------------------------------------------------------
__global__ __launch_bounds__(64) void win_spk(const unsigned char* __restrict__ spk,
                                              float* __restrict__ out)
{
    const int blk = blockIdx.x;              // i*BB + b
    const int i = blk / BB, b = blk - i * BB;
    const int f = threadIdx.x;
    unsigned mask = 0u;
    if (f < NF) {
        const unsigned char* p = spk + (size_t)(i * NBT + b * TT) * NF + f;
        for (int t = 0; t < TT; ++t)
            if (p[(size_t)t * NF]) mask |= (1u << t);
    }
    int c     = __popc(mask);
    int first = TT - c; if (first > TT - 1) first = TT - 1;
    int fv    = (f < NF) ? (int)((mask >> first) & 1u) : 0;
    unsigned long long bal = __ballot(fv != 0);
    int v30 = (bal != 0ull) ? TT : 0;
    int tot = (f < NF) ? c * (fv + v30) : -1;
    int idx = f;
    for (int off = 32; off > 0; off >>= 1) {
        int ot = __shfl_xor(tot, off);
        int oi = __shfl_xor(idx, off);
        if (ot > tot || (ot == tot && oi < idx)) { tot = ot; idx = oi; }
    }
    if (f == 0) out[blk] = (float)((tot > 0) ? idx : -1);
}

// Fallback: winners straight from pots (if ws too small for spike buffer).
__global__ __launch_bounds__(64) void win_pots(float* __restrict__ out)
{
    const int blk = blockIdx.x;
    const int f   = threadIdx.x;
    const float* po = out + WIN_CNT + (size_t)blk * TT * NF * SECLEN;
    unsigned mask = 0u;
    if (f < NF) {
        for (int t = 0; t < TT; ++t) {
            const float4 v = *(const float4*)(po + ((size_t)t * NF + f) * SECLEN);
            float m = fmaxf(fmaxf(v.x, v.y), fmaxf(v.z, v.w));
            if (m >= THRESH) mask |= (1u << t);
        }
    }
    int c     = __popc(mask);
    int first = TT - c; if (first > TT - 1) first = TT - 1;
    int fv    = (f < NF) ? (int)((mask >> first) & 1u) : 0;
    unsigned long long bal = __ballot(fv != 0);
    int v30 = (bal != 0ull) ? TT : 0;
    int tot = (f < NF) ? c * (fv + v30) : -1;
    int idx = f;
    for (int off = 32; off > 0; off >>= 1) {
        int ot = __shfl_xor(tot, off);
        int oi = __shfl_xor(idx, off);
        if (ot > tot || (ot == tot && oi < idx)) { tot = ot; idx = oi; }
    }
    if (f == 0) out[blk] = (float)((tot > 0) ? idx : -1);
}

extern "C" void kernel_launch(void* const* d_in, const int* in_sizes, int n_in,
                              void* d_out, int out_size, void* d_ws, size_t ws_size,
                              hipStream_t stream)
{
    const float* x = (const float*)d_in[0];
    const float* W = (const float*)d_in[1];
    float* out = (float*)d_out;
    unsigned char* wsw = (unsigned char*)d_ws;
    unsigned char* spk = wsw + WSW_BYTES;
    const bool use_spk = ws_size >= (size_t)(WSW_BYTES + SPK_BYTES);

    wconv_kernel<<<(NSEC*4*8*64) / 256, 256, 0, stream>>>(W, wsw);
    if (use_spk) {
        pots_mfma<true><<<NSEC * NBTBLK, 512, 0, stream>>>(x, wsw, out, spk);
        win_spk<<<NSEC * BB, 64, 0, stream>>>(spk, out);
    } else {
        pots_mfma<false><<<NSEC * NBTBLK, 512, 0, stream>>>(x, wsw, out, nullptr);
        win_pots<<<NSEC * BB, 64, 0, stream>>>(out);
    }
}